// Round 8
// baseline (103.425 us; speedup 1.0000x reference)
//
#include <hip/hip_runtime.h>
#include <math.h>

#define NB 4
#define NN 512
#define ND 128
#define NC 10
#define TI 16          // square tile edge
#define NTILE (NN/TI)  // 32
#define TPB (NTILE*(NTILE+1)/2)   // 528 tile-pairs per batch (upper triangle incl diag)
#define PAD 132
#define CHUNKS (ND/4)  // 32

// one direction's span-dependent epilogue (focal loss + counters)
static __device__ __forceinline__ void dir_epilogue(
    const float (&l)[NC], const float (&e)[NC], float mx, float lgs, float inv,
    int pred, bool v, int sp,
    float& lsum, float& accn, float& tpn, float& tnn, float& fpn)
{
    float lsp = l[0], esp = e[0];
    #pragma unroll
    for (int c = 1; c < NC; ++c) {
        lsp = (sp == c) ? l[c] : lsp;
        esp = (sp == c) ? e[c] : esp;
    }
    const float lp   = (lsp - mx) - lgs;   // log(prob)
    const float prob = esp * inv;
    const float om   = 1.f - prob;
    const float lm   = -(om * om) * lp;    // focal loss term
    if (v) { lsum += lm; if (pred == sp) accn += 1.f; }
    if (sp > 0) { if (pred == sp) tpn += 1.f; else tnn += 1.f; }
    else if (pred > 0 && v) fpn += 1.f;
}

__global__ __launch_bounds__(256) void w2ner_main(
    const float* __restrict__ x, const int* __restrict__ span,
    const int* __restrict__ seqlen, const float* __restrict__ Wm,
    const float* __restrict__ bias, float* __restrict__ out,
    float* __restrict__ accum, int use_slots)
{
    __shared__ float sXj[TI * PAD];
    __shared__ float sRed[4 * 5];

    const int tid = threadIdx.x;
    const int blk = blockIdx.x;
    const int b   = blk / TPB;
    int m = blk % TPB;

    // map m -> (Ti, Tj) with Tj >= Ti (upper-triangle tile pairs)
    int Ti = 0;
    while (m >= (NTILE - Ti)) { m -= (NTILE - Ti); ++Ti; }
    const int Tj = Ti + m;
    const bool mirror = (Tj > Ti);

    const int i0 = Ti * TI, j0 = Tj * TI;
    const float* xb = x + (size_t)b * NN * ND;

    // stage Xj tile (16 rows, coalesced float4)
    for (int idx = tid; idx < TI * (ND / 4); idx += 256) {
        int row = idx >> 5, c4 = (idx & 31) << 2;
        float4 v = *reinterpret_cast<const float4*>(xb + (size_t)(j0 + row) * ND + c4);
        *reinterpret_cast<float4*>(sXj + row * PAD + c4) = v;
    }

    const int r  = tid >> 4;   // i-row within tile
    const int cc = tid & 15;   // j-col within tile
    const int i = i0 + r, j = j0 + cc;

    // prefetch span (both directions) before the K-loop; latency hides under FMA
    const size_t offA = (size_t)b * NN * NN + (size_t)i * NN + j;
    const int spA = span[offA];
    size_t offB = 0; int spB = 0;
    if (mirror) { offB = (size_t)b * NN * NN + (size_t)j * NN + i; spB = span[offB]; }
    const int sl = seqlen[b];

    __syncthreads();

    float acc[NC];
    #pragma unroll
    for (int c = 0; c < NC; ++c) acc[c] = 0.f;

    // Xi per-lane from global: 16 lanes share each address -> broadcast (L1/L2 hot).
    // Xj from LDS (pure-ds lgkm queue -> fine-grained counted waits).
    // W: launder the base pointer into a VGPR so the compiler CANNOT prove the
    // address wave-uniform -> emits global_load_dwordx4 (vmcnt queue, in-order,
    // counted waits) instead of s_load (SMEM, out-of-order, forces lgkmcnt(0)
    // drains and is SGPR-starved at 40 SGPR/chunk).
    const float* gXi = xb + (size_t)i * ND;
    const float* pXj = sXj + cc * PAD;
    const float* wbase = Wm;
    asm("" : "+v"(wbase));   // force vector-register base -> VMEM path for W

    #pragma unroll 4
    for (int t = 0; t < CHUNKS; ++t) {
        float4 a  = *reinterpret_cast<const float4*>(gXi + 4 * t);
        float4 bq = *reinterpret_cast<const float4*>(pXj + 4 * t);
        float w[40];
        const float4* wp = reinterpret_cast<const float4*>(wbase + 40 * t);
        #pragma unroll
        for (int mm = 0; mm < 10; ++mm)
            *reinterpret_cast<float4*>(&w[4 * mm]) = wp[mm];
        float pr[4] = { a.x * bq.x, a.y * bq.y, a.z * bq.z, a.w * bq.w };
        #pragma unroll
        for (int dd = 0; dd < 4; ++dd)
            #pragma unroll
            for (int c = 0; c < NC; ++c)
                acc[c] = fmaf(pr[dd], w[dd * NC + c], acc[c]);
    }

    // shared (symmetric) part of the epilogue
    float l[NC];
    #pragma unroll
    for (int c = 0; c < NC; ++c) l[c] = acc[c] + bias[c];
    int am = 0; float mx = l[0];
    #pragma unroll
    for (int c = 1; c < NC; ++c) { if (l[c] > mx) { mx = l[c]; am = c; } }   // first-occurrence argmax
    float e[NC]; float s = 0.f;
    #pragma unroll
    for (int c = 0; c < NC; ++c) { e[c] = __expf(l[c] - mx); s += e[c]; }
    const float inv = __builtin_amdgcn_rcpf(s);
    const float lgs = __logf(s);
    const bool v = (i < sl) && (j < sl);
    const int pred = v ? am : 0;

    float lsum = 0.f, accn = 0.f, tpn = 0.f, tnn = 0.f, fpn = 0.f;
    out[offA] = (float)pred;
    dir_epilogue(l, e, mx, lgs, inv, pred, v, spA, lsum, accn, tpn, tnn, fpn);
    if (mirror) {
        out[offB] = (float)pred;   // predict is symmetric
        dir_epilogue(l, e, mx, lgs, inv, pred, v, spB, lsum, accn, tpn, tnn, fpn);
    }

    // block reduction: 5 partials
    float vals[5] = { lsum, accn, tpn, tnn, fpn };
    #pragma unroll
    for (int k = 0; k < 5; ++k) {
        float vv = vals[k];
        for (int o = 32; o > 0; o >>= 1) vv += __shfl_down(vv, o);
        vals[k] = vv;
    }
    const int wave = tid >> 6;
    const int lane = tid & 63;
    if (lane == 0) {
        #pragma unroll
        for (int k = 0; k < 5; ++k) sRed[wave * 5 + k] = vals[k];
    }
    __syncthreads();
    if (tid < 5) {
        float t = sRed[tid] + sRed[5 + tid] + sRed[10 + tid] + sRed[15 + tid];
        if (use_slots) accum[(size_t)blk * 5 + tid] = t;
        else atomicAdd(&accum[tid], t);
    }
}

__global__ __launch_bounds__(256) void w2ner_final(
    const int* __restrict__ seqlen, const float* __restrict__ accum,
    float* __restrict__ out, int use_slots)
{
    __shared__ float sP[4][5];
    const int tid = threadIdx.x;
    const int nblk = NB * TPB;   // 2112
    float part[5] = {0.f, 0.f, 0.f, 0.f, 0.f};
    if (use_slots) {
        for (int r = tid; r < nblk; r += 256) {
            #pragma unroll
            for (int k = 0; k < 5; ++k) part[k] += accum[(size_t)r * 5 + k];
        }
    }
    #pragma unroll
    for (int k = 0; k < 5; ++k) {
        float v = part[k];
        for (int o = 32; o > 0; o >>= 1) v += __shfl_down(v, o);
        part[k] = v;
    }
    const int wave = tid >> 6;
    const int lane = tid & 63;
    if (lane == 0) {
        #pragma unroll
        for (int k = 0; k < 5; ++k) sP[wave][k] = part[k];
    }
    __syncthreads();
    if (tid == 0) {
        float t[5];
        #pragma unroll
        for (int k = 0; k < 5; ++k)
            t[k] = use_slots ? (sP[0][k] + sP[1][k] + sP[2][k] + sP[3][k]) : accum[k];
        float s2 = 0.f;
        for (int k = 0; k < NB; ++k) { float s = (float)seqlen[k]; s2 += s * s; }
        const size_t base = (size_t)NB * NN * NN;
        out[base + 0] = t[2];          // tp
        out[base + 1] = t[3];          // tn
        out[base + 2] = t[4];          // fp
        out[base + 3] = t[0] / s2;     // loss
        out[base + 4] = t[1] / s2;     // accuracy
    }
}

extern "C" void kernel_launch(void* const* d_in, const int* in_sizes, int n_in,
                              void* d_out, int out_size, void* d_ws, size_t ws_size,
                              hipStream_t stream) {
    const float* x      = (const float*)d_in[0];
    const int*   span   = (const int*)d_in[1];
    const int*   seqlen = (const int*)d_in[2];
    const float* Wm     = (const float*)d_in[3];
    const float* bias   = (const float*)d_in[4];
    float* out   = (float*)d_out;
    float* accum = (float*)d_ws;

    const int nblk = NB * TPB;                         // 2112 blocks
    const size_t need = (size_t)nblk * 5 * sizeof(float);
    const int use_slots = (ws_size >= need) ? 1 : 0;
    if (!use_slots) hipMemsetAsync(accum, 0, 5 * sizeof(float), stream);

    w2ner_main<<<dim3(nblk), 256, 0, stream>>>(x, span, seqlen, Wm, bias, out, accum, use_slots);
    w2ner_final<<<1, 256, 0, stream>>>(seqlen, accum, out, use_slots);
}

// Round 9
// 40.577 us; speedup vs baseline: 2.5488x; 2.5488x over previous
//
#include <hip/hip_runtime.h>
#include <math.h>

#define NB 4
#define NN 512
#define ND 128
#define NC 10
#define NT 32                 // 16-row tiles per side (512/16)
#define NYW (NB*NT*NC*4)      // 5120 y-frag waves/frags
#define NXW (NB*NT*4)         // 512 x-frag waves/frags
#define NBLK_M (NB*NT*8)      // 1024 main blocks: (b,Tj,TiG)

typedef short bf16x8 __attribute__((ext_vector_type(8)));
typedef float f32x4 __attribute__((ext_vector_type(4)));

static __device__ __forceinline__ unsigned short f2bf(float f) {
    unsigned u = __builtin_bit_cast(unsigned, f);
    u += 0x7FFFu + ((u >> 16) & 1u);      // RNE
    return (unsigned short)(u >> 16);
}
static __device__ __forceinline__ float bf2f(unsigned short h) {
    unsigned u = ((unsigned)h) << 16;
    return __builtin_bit_cast(float, u);
}

// ---------------- P: pre-fragment x (A-operand) and y = x*W (B-operand) ----------------
// Frag layout (16x16x32 bf16 MFMA, one frag = 64 lanes x 8 bf16 = 1KB):
//   A-frag (x side): lane l holds x[row = base + (l&15)][k = 32g + 8*(l>>4) + e]
//   B-frag (y side): lane l holds y[col = base + (l&15)][k likewise]  (B^T, k-contiguous)
// k-enumeration within a frag is identical for A and B, so any consistent bijection works.
__global__ __launch_bounds__(256) void w2ner_prep(
    const float* __restrict__ x, const float* __restrict__ Wm,
    short* __restrict__ YH, short* __restrict__ YL,
    short* __restrict__ XH, short* __restrict__ XL)
{
    const int tid = threadIdx.x;
    const int w = blockIdx.x * 4 + (tid >> 6);
    const int l = tid & 63;
    const int jl = l & 15, kg = l >> 4;
    if (w < NYW) {
        const int g = w & 3; int t = w >> 2;
        const int c = t % 10; int u = t / 10;
        const int J = u & 31, b = u >> 5;
        const int j = J * 16 + jl, d0 = 32 * g + 8 * kg;
        const float* xr = x + ((size_t)b * NN + j) * ND + d0;
        float xv[8];
        *(float4*)&xv[0] = *(const float4*)xr;
        *(float4*)&xv[4] = *(const float4*)(xr + 4);
        short hi[8], lo[8];
        #pragma unroll
        for (int e = 0; e < 8; ++e) {
            float yv = xv[e] * Wm[(d0 + e) * NC + c];
            unsigned short h = f2bf(yv);
            hi[e] = (short)h;
            lo[e] = (short)f2bf(yv - bf2f(h));
        }
        size_t fo = ((size_t)w * 64 + l) * 8;
        *(bf16x8*)(YH + fo) = *(bf16x8*)hi;
        *(bf16x8*)(YL + fo) = *(bf16x8*)lo;
    } else {
        const int w2 = w - NYW;
        const int g = w2 & 3; int v = w2 >> 2;
        const int I = v & 31, b = v >> 5;
        const int i = I * 16 + jl, d0 = 32 * g + 8 * kg;
        const float* xr = x + ((size_t)b * NN + i) * ND + d0;
        float xv[8];
        *(float4*)&xv[0] = *(const float4*)xr;
        *(float4*)&xv[4] = *(const float4*)(xr + 4);
        short hi[8], lo[8];
        #pragma unroll
        for (int e = 0; e < 8; ++e) {
            unsigned short h = f2bf(xv[e]);
            hi[e] = (short)h;
            lo[e] = (short)f2bf(xv[e] - bf2f(h));
        }
        size_t fo = ((size_t)w2 * 64 + l) * 8;
        *(bf16x8*)(XH + fo) = *(bf16x8*)hi;
        *(bf16x8*)(XL + fo) = *(bf16x8*)lo;
    }
}

// ---------------- M: MFMA GEMM + fused softmax/focal epilogue ----------------
__global__ __launch_bounds__(256) void w2ner_mfma(
    const short* __restrict__ YHp, const short* __restrict__ YLp,
    const short* __restrict__ XHp, const short* __restrict__ XLp,
    const int* __restrict__ span, const int* __restrict__ seqlen,
    const float* __restrict__ bias, float* __restrict__ out,
    float* __restrict__ accum)
{
    __shared__ float sRed[4 * 5];
    const int tid = threadIdx.x;
    const int blk = blockIdx.x;
    const int TiG = blk & 7; const int u = blk >> 3;
    const int Tj = u & 31;   const int b = u >> 5;
    const int wv = tid >> 6, l = tid & 63;
    const int Ti = TiG * 4 + wv;

    const bf16x8* yh = (const bf16x8*)YHp;
    const bf16x8* yl = (const bf16x8*)YLp;
    const bf16x8* xh = (const bf16x8*)XHp;
    const bf16x8* xl = (const bf16x8*)XLp;

    const int jl = l & 15, rg = l >> 4;
    const int j  = Tj * 16 + jl;
    const int ib = Ti * 16 + rg * 4;   // D-tile rows: (lane>>4)*4 + reg  [m89-verified]
    const int sl = seqlen[b];

    // prefetch span for the 4 pairs this lane owns
    int sp[4]; size_t offs[4];
    #pragma unroll
    for (int r = 0; r < 4; ++r) {
        offs[r] = (size_t)b * NN * NN + (size_t)(ib + r) * NN + j;
        sp[r] = span[offs[r]];
    }

    f32x4 acc[NC];
    #pragma unroll
    for (int c = 0; c < NC; ++c) acc[c] = (f32x4){0.f, 0.f, 0.f, 0.f};

    const int ybase = (b * NT + Tj) * NC * 4;   // frag id (c,g) = ybase + c*4 + g
    const int abase = (b * NT + Ti) * 4;        // frag id (g)   = abase + g

    #pragma unroll
    for (int g = 0; g < 4; ++g) {
        bf16x8 ah = xh[(size_t)(abase + g) * 64 + l];
        bf16x8 al = xl[(size_t)(abase + g) * 64 + l];
        #pragma unroll
        for (int c = 0; c < NC; ++c) {
            bf16x8 bh = yh[(size_t)(ybase + c * 4 + g) * 64 + l];
            bf16x8 bl = yl[(size_t)(ybase + c * 4 + g) * 64 + l];
            // bf16x3 split: hi*hi + lo*hi + hi*lo (lo*lo ~2^-18, dropped)
            acc[c] = __builtin_amdgcn_mfma_f32_16x16x32_bf16(ah, bh, acc[c], 0, 0, 0);
            acc[c] = __builtin_amdgcn_mfma_f32_16x16x32_bf16(al, bh, acc[c], 0, 0, 0);
            acc[c] = __builtin_amdgcn_mfma_f32_16x16x32_bf16(ah, bl, acc[c], 0, 0, 0);
        }
    }

    float lsum = 0.f, accn = 0.f, tpn = 0.f, tnn = 0.f, fpn = 0.f;
    #pragma unroll
    for (int r = 0; r < 4; ++r) {
        const int i = ib + r;
        float L[NC];
        #pragma unroll
        for (int c = 0; c < NC; ++c) L[c] = acc[c][r] + bias[c];
        int am = 0; float mx = L[0];
        #pragma unroll
        for (int c = 1; c < NC; ++c) { if (L[c] > mx) { mx = L[c]; am = c; } }  // first-occurrence argmax
        float e[NC]; float s = 0.f;
        #pragma unroll
        for (int c = 0; c < NC; ++c) { e[c] = __expf(L[c] - mx); s += e[c]; }
        const int spv = sp[r];
        float lsp = L[0], esp = e[0];
        #pragma unroll
        for (int c = 1; c < NC; ++c) {
            lsp = (spv == c) ? L[c] : lsp;
            esp = (spv == c) ? e[c] : esp;
        }
        const float inv  = __builtin_amdgcn_rcpf(s);
        const float lp   = (lsp - mx) - __logf(s);
        const float prob = esp * inv;
        const float om   = 1.f - prob;
        const float lm   = -(om * om) * lp;
        const bool v = (i < sl) && (j < sl);
        const int pred = v ? am : 0;
        out[offs[r]] = (float)pred;
        if (v) { lsum += lm; if (pred == spv) accn += 1.f; }
        if (spv > 0) { if (pred == spv) tpn += 1.f; else tnn += 1.f; }
        else if (pred > 0 && v) fpn += 1.f;
    }

    float vals[5] = { lsum, accn, tpn, tnn, fpn };
    #pragma unroll
    for (int k = 0; k < 5; ++k) {
        float vv = vals[k];
        for (int o = 32; o > 0; o >>= 1) vv += __shfl_down(vv, o);
        vals[k] = vv;
    }
    const int lane = tid & 63;
    if (lane == 0) {
        #pragma unroll
        for (int k = 0; k < 5; ++k) sRed[wv * 5 + k] = vals[k];
    }
    __syncthreads();
    if (tid < 5) {
        float t = sRed[tid] + sRed[5 + tid] + sRed[10 + tid] + sRed[15 + tid];
        accum[(size_t)blk * 5 + tid] = t;
    }
}

__global__ __launch_bounds__(256) void w2ner_final(
    const int* __restrict__ seqlen, const float* __restrict__ accum,
    float* __restrict__ out)
{
    __shared__ float sP[4][5];
    const int tid = threadIdx.x;
    float part[5] = {0.f, 0.f, 0.f, 0.f, 0.f};
    for (int r = tid; r < NBLK_M; r += 256) {
        #pragma unroll
        for (int k = 0; k < 5; ++k) part[k] += accum[(size_t)r * 5 + k];
    }
    #pragma unroll
    for (int k = 0; k < 5; ++k) {
        float v = part[k];
        for (int o = 32; o > 0; o >>= 1) v += __shfl_down(v, o);
        part[k] = v;
    }
    const int wave = tid >> 6;
    const int lane = tid & 63;
    if (lane == 0) {
        #pragma unroll
        for (int k = 0; k < 5; ++k) sP[wave][k] = part[k];
    }
    __syncthreads();
    if (tid == 0) {
        float t[5];
        #pragma unroll
        for (int k = 0; k < 5; ++k) t[k] = sP[0][k] + sP[1][k] + sP[2][k] + sP[3][k];
        float s2 = 0.f;
        for (int k = 0; k < NB; ++k) { float s = (float)seqlen[k]; s2 += s * s; }
        const size_t base = (size_t)NB * NN * NN;
        out[base + 0] = t[2];          // tp
        out[base + 1] = t[3];          // tn
        out[base + 2] = t[4];          // fp
        out[base + 3] = t[0] / s2;     // loss
        out[base + 4] = t[1] / s2;     // accuracy
    }
}

extern "C" void kernel_launch(void* const* d_in, const int* in_sizes, int n_in,
                              void* d_out, int out_size, void* d_ws, size_t ws_size,
                              hipStream_t stream) {
    const float* x      = (const float*)d_in[0];
    const int*   span   = (const int*)d_in[1];
    const int*   seqlen = (const int*)d_in[2];
    const float* Wm     = (const float*)d_in[3];
    const float* bias   = (const float*)d_in[4];
    float* out = (float*)d_out;

    char* ws = (char*)d_ws;
    short* YH = (short*)(ws);                                   // 5120 frags * 1KB = 5.24 MB
    short* YL = (short*)(ws + ((size_t)6 << 20));               // 5.24 MB
    short* XH = (short*)(ws + ((size_t)12 << 20));              // 512 KB
    short* XL = (short*)(ws + ((size_t)12 << 20) + (1u << 19)); // 512 KB
    float* accum = (float*)(ws + ((size_t)13 << 20));           // 1024*5 f32

    const int pblk = (NYW + NXW) / 4;   // 1408
    w2ner_prep<<<dim3(pblk), 256, 0, stream>>>(x, Wm, YH, YL, XH, XL);
    w2ner_mfma<<<dim3(NBLK_M), 256, 0, stream>>>(YH, YL, XH, XL, span, seqlen,
                                                 bias, out, accum);
    w2ner_final<<<1, 256, 0, stream>>>(seqlen, accum, out);
}

// Round 10
// 35.128 us; speedup vs baseline: 2.9443x; 1.1551x over previous
//
#include <hip/hip_runtime.h>
#include <math.h>

#define NB 4
#define NN 512
#define ND 128
#define NC 10
#define NT 32                 // 16-row tiles per side (512/16)
#define NYW (NB*NT*NC*4)      // 5120 y-frags
#define NXW (NB*NT*4)         // 512 x-frags
#define MREP 2                // i-tiles per wave
#define NBLK_M (NB*NT*4)      // 512 main blocks: (b,Tj,q)  q = group of 8 i-tiles

typedef short bf16x8 __attribute__((ext_vector_type(8)));
typedef float f32x4 __attribute__((ext_vector_type(4)));

static __device__ __forceinline__ unsigned short f2bf(float f) {
    unsigned u = __builtin_bit_cast(unsigned, f);
    u += 0x7FFFu + ((u >> 16) & 1u);      // RNE
    return (unsigned short)(u >> 16);
}
static __device__ __forceinline__ float bf2f(unsigned short h) {
    unsigned u = ((unsigned)h) << 16;
    return __builtin_bit_cast(float, u);
}

// ---------------- P: pre-fragment x (A-operand) and y = x*W (B-operand) ----------------
// Frag layout (16x16x32 bf16 MFMA, one frag = 64 lanes x 8 bf16 = 1KB):
//   A-frag: lane l holds x[row = base + (l&15)][k = 32g + 8*(l>>4) + e]
//   B-frag: lane l holds y[col = base + (l&15)][k likewise]
// k-enumeration identical for A and B -> any consistent bijection works. (r9-verified, absmax 4)
__global__ __launch_bounds__(256) void w2ner_prep(
    const float* __restrict__ x, const float* __restrict__ Wm,
    short* __restrict__ YH, short* __restrict__ YL,
    short* __restrict__ XH, short* __restrict__ XL)
{
    const int tid = threadIdx.x;
    const int w = blockIdx.x * 4 + (tid >> 6);
    const int l = tid & 63;
    const int jl = l & 15, kg = l >> 4;
    if (w < NYW) {
        const int g = w & 3; int t = w >> 2;
        const int c = t % 10; int u = t / 10;
        const int J = u & 31, b = u >> 5;
        const int j = J * 16 + jl, d0 = 32 * g + 8 * kg;
        const float* xr = x + ((size_t)b * NN + j) * ND + d0;
        float xv[8];
        *(float4*)&xv[0] = *(const float4*)xr;
        *(float4*)&xv[4] = *(const float4*)(xr + 4);
        short hi[8], lo[8];
        #pragma unroll
        for (int e = 0; e < 8; ++e) {
            float yv = xv[e] * Wm[(d0 + e) * NC + c];
            unsigned short h = f2bf(yv);
            hi[e] = (short)h;
            lo[e] = (short)f2bf(yv - bf2f(h));
        }
        size_t fo = ((size_t)w * 64 + l) * 8;
        *(bf16x8*)(YH + fo) = *(bf16x8*)hi;
        *(bf16x8*)(YL + fo) = *(bf16x8*)lo;
    } else {
        const int w2 = w - NYW;
        const int g = w2 & 3; int v = w2 >> 2;
        const int I = v & 31, b = v >> 5;
        const int i = I * 16 + jl, d0 = 32 * g + 8 * kg;
        const float* xr = x + ((size_t)b * NN + i) * ND + d0;
        float xv[8];
        *(float4*)&xv[0] = *(const float4*)xr;
        *(float4*)&xv[4] = *(const float4*)(xr + 4);
        short hi[8], lo[8];
        #pragma unroll
        for (int e = 0; e < 8; ++e) {
            unsigned short h = f2bf(xv[e]);
            hi[e] = (short)h;
            lo[e] = (short)f2bf(xv[e] - bf2f(h));
        }
        size_t fo = ((size_t)w2 * 64 + l) * 8;
        *(bf16x8*)(XH + fo) = *(bf16x8*)hi;
        *(bf16x8*)(XL + fo) = *(bf16x8*)lo;
    }
}

// ---------------- M: MFMA GEMM (2 i-tiles/wave) + fused softmax/focal epilogue ----------------
__global__ __launch_bounds__(256) void w2ner_mfma(
    const short* __restrict__ YHp, const short* __restrict__ YLp,
    const short* __restrict__ XHp, const short* __restrict__ XLp,
    const int* __restrict__ span, const int* __restrict__ seqlen,
    const float* __restrict__ bias, float* __restrict__ out,
    float* __restrict__ accum)
{
    __shared__ float sRed[4 * 5];
    const int tid = threadIdx.x;
    // XCD co-location: hw blocks with blk%8==k get logical lb in [64k, 64k+64) ->
    // the 4 blocks sharing (b,Tj) run on ONE XCD, Y-set (80KB) stays L2-resident.
    const int lb = (blockIdx.x & 7) * (NBLK_M / 8) + (blockIdx.x >> 3);
    const int q  = lb & 3;              // i-tile octet
    const int Tj = (lb >> 2) & 31;
    const int b  = lb >> 7;
    const int wv = tid >> 6, l = tid & 63;
    const int Ti0 = q * 8 + wv * MREP;  // wave's first i-tile

    const bf16x8* yh = (const bf16x8*)YHp;
    const bf16x8* yl = (const bf16x8*)YLp;
    const bf16x8* xh = (const bf16x8*)XHp;
    const bf16x8* xl = (const bf16x8*)XLp;

    const int jl = l & 15, rg = l >> 4;
    const int j  = Tj * 16 + jl;
    const int sl = seqlen[b];

    // prefetch span for the 8 pairs this lane owns (hides under MFMA loop)
    int sp[MREP][4];
    #pragma unroll
    for (int m = 0; m < MREP; ++m) {
        const int ib = (Ti0 + m) * 16 + rg * 4;
        #pragma unroll
        for (int r = 0; r < 4; ++r)
            sp[m][r] = span[(size_t)b * NN * NN + (size_t)(ib + r) * NN + j];
    }

    f32x4 acc[MREP][NC];
    #pragma unroll
    for (int m = 0; m < MREP; ++m)
        #pragma unroll
        for (int c = 0; c < NC; ++c) acc[m][c] = (f32x4){0.f, 0.f, 0.f, 0.f};

    const int ybase = (b * NT + Tj) * NC * 4;   // frag id (c,g) = ybase + c*4 + g

    #pragma unroll
    for (int g = 0; g < 4; ++g) {
        bf16x8 ah[MREP], al[MREP];
        #pragma unroll
        for (int m = 0; m < MREP; ++m) {
            const int af = (b * NT + Ti0 + m) * 4 + g;
            ah[m] = xh[(size_t)af * 64 + l];
            al[m] = xl[(size_t)af * 64 + l];
        }
        #pragma unroll
        for (int c = 0; c < NC; ++c) {
            bf16x8 bh = yh[(size_t)(ybase + c * 4 + g) * 64 + l];
            bf16x8 bl = yl[(size_t)(ybase + c * 4 + g) * 64 + l];
            #pragma unroll
            for (int m = 0; m < MREP; ++m) {
                // bf16x3: hi*hi + lo*hi + hi*lo (lo*lo ~2^-18, dropped)
                acc[m][c] = __builtin_amdgcn_mfma_f32_16x16x32_bf16(ah[m], bh, acc[m][c], 0, 0, 0);
                acc[m][c] = __builtin_amdgcn_mfma_f32_16x16x32_bf16(al[m], bh, acc[m][c], 0, 0, 0);
                acc[m][c] = __builtin_amdgcn_mfma_f32_16x16x32_bf16(ah[m], bl, acc[m][c], 0, 0, 0);
            }
        }
    }

    float lsum = 0.f, accn = 0.f, tpn = 0.f, tnn = 0.f, fpn = 0.f;
    #pragma unroll
    for (int m = 0; m < MREP; ++m) {
        const int ib = (Ti0 + m) * 16 + rg * 4;   // C/D rows: (lane>>4)*4 + reg [r9-verified]
        #pragma unroll
        for (int r = 0; r < 4; ++r) {
            const int i = ib + r;
            float L[NC];
            #pragma unroll
            for (int c = 0; c < NC; ++c) L[c] = acc[m][c][r] + bias[c];
            int am = 0; float mx = L[0];
            #pragma unroll
            for (int c = 1; c < NC; ++c) { if (L[c] > mx) { mx = L[c]; am = c; } }  // first-occurrence argmax
            float e[NC]; float s = 0.f;
            #pragma unroll
            for (int c = 0; c < NC; ++c) { e[c] = __expf(L[c] - mx); s += e[c]; }
            const int spv = sp[m][r];
            float lsp = L[0], esp = e[0];
            #pragma unroll
            for (int c = 1; c < NC; ++c) {
                lsp = (spv == c) ? L[c] : lsp;
                esp = (spv == c) ? e[c] : esp;
            }
            const float inv  = __builtin_amdgcn_rcpf(s);
            const float lp   = (lsp - mx) - __logf(s);
            const float prob = esp * inv;
            const float om   = 1.f - prob;
            const float lm   = -(om * om) * lp;
            const bool v = (i < sl) && (j < sl);
            const int pred = v ? am : 0;
            out[(size_t)b * NN * NN + (size_t)i * NN + j] = (float)pred;
            if (v) { lsum += lm; if (pred == spv) accn += 1.f; }
            if (spv > 0) { if (pred == spv) tpn += 1.f; else tnn += 1.f; }
            else if (pred > 0 && v) fpn += 1.f;
        }
    }

    float vals[5] = { lsum, accn, tpn, tnn, fpn };
    #pragma unroll
    for (int k = 0; k < 5; ++k) {
        float vv = vals[k];
        for (int o = 32; o > 0; o >>= 1) vv += __shfl_down(vv, o);
        vals[k] = vv;
    }
    if (l == 0) {
        #pragma unroll
        for (int k = 0; k < 5; ++k) sRed[wv * 5 + k] = vals[k];
    }
    __syncthreads();
    if (tid < 5) {
        float t = sRed[tid] + sRed[5 + tid] + sRed[10 + tid] + sRed[15 + tid];
        accum[(size_t)blockIdx.x * 5 + tid] = t;
    }
}

__global__ __launch_bounds__(256) void w2ner_final(
    const int* __restrict__ seqlen, const float* __restrict__ accum,
    float* __restrict__ out)
{
    __shared__ float sP[4][5];
    const int tid = threadIdx.x;
    float part[5] = {0.f, 0.f, 0.f, 0.f, 0.f};
    for (int r = tid; r < NBLK_M; r += 256) {
        #pragma unroll
        for (int k = 0; k < 5; ++k) part[k] += accum[(size_t)r * 5 + k];
    }
    #pragma unroll
    for (int k = 0; k < 5; ++k) {
        float v = part[k];
        for (int o = 32; o > 0; o >>= 1) v += __shfl_down(v, o);
        part[k] = v;
    }
    const int wave = tid >> 6;
    const int lane = tid & 63;
    if (lane == 0) {
        #pragma unroll
        for (int k = 0; k < 5; ++k) sP[wave][k] = part[k];
    }
    __syncthreads();
    if (tid == 0) {
        float t[5];
        #pragma unroll
        for (int k = 0; k < 5; ++k) t[k] = sP[0][k] + sP[1][k] + sP[2][k] + sP[3][k];
        float s2 = 0.f;
        for (int k = 0; k < NB; ++k) { float s = (float)seqlen[k]; s2 += s * s; }
        const size_t base = (size_t)NB * NN * NN;
        out[base + 0] = t[2];          // tp
        out[base + 1] = t[3];          // tn
        out[base + 2] = t[4];          // fp
        out[base + 3] = t[0] / s2;     // loss
        out[base + 4] = t[1] / s2;     // accuracy
    }
}

extern "C" void kernel_launch(void* const* d_in, const int* in_sizes, int n_in,
                              void* d_out, int out_size, void* d_ws, size_t ws_size,
                              hipStream_t stream) {
    const float* x      = (const float*)d_in[0];
    const int*   span   = (const int*)d_in[1];
    const int*   seqlen = (const int*)d_in[2];
    const float* Wm     = (const float*)d_in[3];
    const float* bias   = (const float*)d_in[4];
    float* out = (float*)d_out;

    char* ws = (char*)d_ws;
    short* YH = (short*)(ws);                                   // 5120 frags * 1KB = 5.24 MB
    short* YL = (short*)(ws + ((size_t)6 << 20));               // 5.24 MB
    short* XH = (short*)(ws + ((size_t)12 << 20));              // 512 KB
    short* XL = (short*)(ws + ((size_t)12 << 20) + (1u << 19)); // 512 KB
    float* accum = (float*)(ws + ((size_t)13 << 20));           // 512*5 f32

    const int pblk = (NYW + NXW) / 4;   // 1408
    w2ner_prep<<<dim3(pblk), 256, 0, stream>>>(x, Wm, YH, YL, XH, XL);
    w2ner_mfma<<<dim3(NBLK_M), 256, 0, stream>>>(YH, YL, XH, XL, span, seqlen,
                                                 bias, out, accum);
    w2ner_final<<<1, 256, 0, stream>>>(seqlen, accum, out);
}

// Round 11
// 23.719 us; speedup vs baseline: 4.3603x; 1.4810x over previous
//
#include <hip/hip_runtime.h>
#include <math.h>

#define NB 4
#define NN 512
#define ND 128
#define NC 10
#define NT 32                // 16-wide tiles per side
#define MREP 2               // i-tiles per wave
#define NBLK_M (NB*NT*4)     // 512 blocks: (b, Tj, q); q = octet of i-tiles

typedef short    bf16x8 __attribute__((ext_vector_type(8)));
typedef unsigned u32x4  __attribute__((ext_vector_type(4)));
typedef float    f32x4  __attribute__((ext_vector_type(4)));

// pack two f32 into two truncated bf16 (low short = a, high short = b)
static __device__ __forceinline__ unsigned pack_trunc(float a, float b) {
    unsigned ua = __builtin_bit_cast(unsigned, a);
    unsigned ub = __builtin_bit_cast(unsigned, b);
    return (ua >> 16) | (ub & 0xFFFF0000u);
}

// Fused: build MFMA fragments in-register from x and W, GEMM via 16x16x32 bf16
// MFMA (bf16x2 split: ah*bh + al*bh), fused softmax/focal epilogue.
// Frag semantics identical to the r9/r10-verified layout:
//   A-frag (g): lane l holds x[row = Ti*16 + (l&15)][d = 32g + 8*(l>>4) + e], e=0..7
//   B-frag (c,g): lane l holds y_c[col = Tj*16 + (l&15)][same d-enumeration]
//   C/D: col = lane&15, row = (lane>>4)*4 + reg
__global__ __launch_bounds__(256) void w2ner_fused(
    const float* __restrict__ x, const int* __restrict__ span,
    const int* __restrict__ seqlen, const float* __restrict__ Wm,
    const float* __restrict__ bias, float* __restrict__ out,
    float* __restrict__ accum)
{
    __shared__ float sRed[4 * 5];
    const int tid = threadIdx.x;
    const int blk = blockIdx.x;
    const int q  = blk & 3;
    const int Tj = (blk >> 2) & 31;
    const int b  = blk >> 7;
    const int wv = tid >> 6, l = tid & 63;
    const int jl = l & 15, kg = l >> 4;       // kg doubles as C/D row-group
    const int Ti0 = q * 8 + wv * MREP;
    const int j  = Tj * 16 + jl;
    const int sl = seqlen[b];
    const float* xb = x + (size_t)b * NN * ND;

    // prefetch span for the 8 pairs this lane owns (hides under the main loop)
    int sp[MREP][4];
    #pragma unroll
    for (int m = 0; m < MREP; ++m) {
        const int ib = (Ti0 + m) * 16 + kg * 4;
        #pragma unroll
        for (int r = 0; r < 4; ++r)
            sp[m][r] = span[(size_t)b * NN * NN + (size_t)(ib + r) * NN + j];
    }

    f32x4 acc[MREP][NC];
    #pragma unroll
    for (int m = 0; m < MREP; ++m)
        #pragma unroll
        for (int c = 0; c < NC; ++c) acc[m][c] = (f32x4){0.f, 0.f, 0.f, 0.f};

    #pragma unroll
    for (int g = 0; g < 4; ++g) {
        const int d0 = 32 * g + 8 * kg;

        // B-source row chunk: x[j][d0..d0+8)
        float xj[8];
        *(float4*)&xj[0] = *(const float4*)(xb + (size_t)j * ND + d0);
        *(float4*)&xj[4] = *(const float4*)(xb + (size_t)j * ND + d0 + 4);

        // A fragments: load + exact hi/lo split (truncation; x == hi + lo to 2^-16)
        u32x4 ahw[MREP], alw[MREP];
        #pragma unroll
        for (int m = 0; m < MREP; ++m) {
            const int irow = (Ti0 + m) * 16 + jl;
            float xi[8];
            *(float4*)&xi[0] = *(const float4*)(xb + (size_t)irow * ND + d0);
            *(float4*)&xi[4] = *(const float4*)(xb + (size_t)irow * ND + d0 + 4);
            #pragma unroll
            for (int e2 = 0; e2 < 4; ++e2) {
                const float a0 = xi[2 * e2], a1 = xi[2 * e2 + 1];
                const unsigned u0 = __builtin_bit_cast(unsigned, a0) & 0xFFFF0000u;
                const unsigned u1 = __builtin_bit_cast(unsigned, a1) & 0xFFFF0000u;
                const float h0 = __builtin_bit_cast(float, u0);
                const float h1 = __builtin_bit_cast(float, u1);
                ahw[m][e2] = (u0 >> 16) | u1;
                alw[m][e2] = pack_trunc(a0 - h0, a1 - h1);
            }
        }

        // B fragments (one per class): y = x_j * W, rounded once to bf16 (trunc)
        u32x4 yw[NC];
        #pragma unroll
        for (int e2 = 0; e2 < 4; ++e2) {
            // W rows d0+2e2, d0+2e2+1: 20 contiguous floats, 16B-aligned (d even)
            float wb[20];
            const float4* wp = (const float4*)(Wm + (size_t)(d0 + 2 * e2) * NC);
            #pragma unroll
            for (int t5 = 0; t5 < 5; ++t5) *(float4*)&wb[4 * t5] = wp[t5];
            const float x0 = xj[2 * e2], x1 = xj[2 * e2 + 1];
            #pragma unroll
            for (int c = 0; c < NC; ++c)
                yw[c][e2] = pack_trunc(x0 * wb[c], x1 * wb[10 + c]);
        }

        // MFMAs: 2 per (c, m)
        #pragma unroll
        for (int c = 0; c < NC; ++c) {
            const bf16x8 bh = __builtin_bit_cast(bf16x8, yw[c]);
            #pragma unroll
            for (int m = 0; m < MREP; ++m) {
                const bf16x8 ah = __builtin_bit_cast(bf16x8, ahw[m]);
                const bf16x8 al = __builtin_bit_cast(bf16x8, alw[m]);
                acc[m][c] = __builtin_amdgcn_mfma_f32_16x16x32_bf16(ah, bh, acc[m][c], 0, 0, 0);
                acc[m][c] = __builtin_amdgcn_mfma_f32_16x16x32_bf16(al, bh, acc[m][c], 0, 0, 0);
            }
        }
    }

    float lsum = 0.f, accn = 0.f, tpn = 0.f, tnn = 0.f, fpn = 0.f;
    #pragma unroll
    for (int m = 0; m < MREP; ++m) {
        const int ib = (Ti0 + m) * 16 + kg * 4;   // C/D rows: (lane>>4)*4 + reg
        #pragma unroll
        for (int r = 0; r < 4; ++r) {
            const int i = ib + r;
            float L[NC];
            #pragma unroll
            for (int c = 0; c < NC; ++c) L[c] = acc[m][c][r] + bias[c];
            int am = 0; float mx = L[0];
            #pragma unroll
            for (int c = 1; c < NC; ++c) { if (L[c] > mx) { mx = L[c]; am = c; } }  // first-occurrence argmax
            float e[NC]; float s = 0.f;
            #pragma unroll
            for (int c = 0; c < NC; ++c) { e[c] = __expf(L[c] - mx); s += e[c]; }
            const int spv = sp[m][r];
            float lsp = L[0], esp = e[0];
            #pragma unroll
            for (int c = 1; c < NC; ++c) {
                lsp = (spv == c) ? L[c] : lsp;
                esp = (spv == c) ? e[c] : esp;
            }
            const float inv  = __builtin_amdgcn_rcpf(s);
            const float lp   = (lsp - mx) - __logf(s);
            const float prob = esp * inv;
            const float om   = 1.f - prob;
            const float lm   = -(om * om) * lp;
            const bool v = (i < sl) && (j < sl);
            const int pred = v ? am : 0;
            out[(size_t)b * NN * NN + (size_t)i * NN + j] = (float)pred;
            if (v) { lsum += lm; if (pred == spv) accn += 1.f; }
            if (spv > 0) { if (pred == spv) tpn += 1.f; else tnn += 1.f; }
            else if (pred > 0 && v) fpn += 1.f;
        }
    }

    float vals[5] = { lsum, accn, tpn, tnn, fpn };
    #pragma unroll
    for (int k = 0; k < 5; ++k) {
        float vv = vals[k];
        for (int o = 32; o > 0; o >>= 1) vv += __shfl_down(vv, o);
        vals[k] = vv;
    }
    if (l == 0) {
        #pragma unroll
        for (int k = 0; k < 5; ++k) sRed[wv * 5 + k] = vals[k];
    }
    __syncthreads();
    if (tid < 5) {
        float t = sRed[tid] + sRed[5 + tid] + sRed[10 + tid] + sRed[15 + tid];
        accum[(size_t)blk * 5 + tid] = t;
    }
}

__global__ __launch_bounds__(256) void w2ner_final(
    const int* __restrict__ seqlen, const float* __restrict__ accum,
    float* __restrict__ out)
{
    __shared__ float sP[4][5];
    const int tid = threadIdx.x;
    float part[5] = {0.f, 0.f, 0.f, 0.f, 0.f};
    for (int r = tid; r < NBLK_M; r += 256) {
        #pragma unroll
        for (int k = 0; k < 5; ++k) part[k] += accum[(size_t)r * 5 + k];
    }
    #pragma unroll
    for (int k = 0; k < 5; ++k) {
        float v = part[k];
        for (int o = 32; o > 0; o >>= 1) v += __shfl_down(v, o);
        part[k] = v;
    }
    const int wave = tid >> 6;
    const int lane = tid & 63;
    if (lane == 0) {
        #pragma unroll
        for (int k = 0; k < 5; ++k) sP[wave][k] = part[k];
    }
    __syncthreads();
    if (tid == 0) {
        float t[5];
        #pragma unroll
        for (int k = 0; k < 5; ++k) t[k] = sP[0][k] + sP[1][k] + sP[2][k] + sP[3][k];
        float s2 = 0.f;
        for (int k = 0; k < NB; ++k) { float s = (float)seqlen[k]; s2 += s * s; }
        const size_t base = (size_t)NB * NN * NN;
        out[base + 0] = t[2];          // tp
        out[base + 1] = t[3];          // tn
        out[base + 2] = t[4];          // fp
        out[base + 3] = t[0] / s2;     // loss
        out[base + 4] = t[1] / s2;     // accuracy
    }
}

extern "C" void kernel_launch(void* const* d_in, const int* in_sizes, int n_in,
                              void* d_out, int out_size, void* d_ws, size_t ws_size,
                              hipStream_t stream) {
    const float* x      = (const float*)d_in[0];
    const int*   span   = (const int*)d_in[1];
    const int*   seqlen = (const int*)d_in[2];
    const float* Wm     = (const float*)d_in[3];
    const float* bias   = (const float*)d_in[4];
    float* out   = (float*)d_out;
    float* accum = (float*)d_ws;   // 512*5 f32, fully overwritten each launch

    w2ner_fused<<<dim3(NBLK_M), 256, 0, stream>>>(x, span, seqlen, Wm, bias, out, accum);
    w2ner_final<<<1, 256, 0, stream>>>(seqlen, accum, out);
}